// Round 1
// baseline (20990.410 us; speedup 1.0000x reference)
//
#include <hip/hip_runtime.h>
#include <hip/hip_bf16.h>

#define B_ 64
#define T_ 1024
#define D_ 512
#define H_ 512
#define O_ 512
#define NBLK 32   // j-slice blocks in recurrent kernel

using bf16x8 = __attribute__((ext_vector_type(8))) short;
using f32x4  = __attribute__((ext_vector_type(4))) float;

__device__ __forceinline__ short f2bfs(float f) {
  return (short)__builtin_bit_cast(unsigned short, __float2bfloat16(f));
}

__device__ __forceinline__ float sigmoid_f(float v) {
  return 1.0f / (1.0f + __expf(-v));
}
__device__ __forceinline__ float tanh_f(float v) {
  float a = fabsf(v);
  float e = __expf(-2.0f * a);
  float t = (1.0f - e) / (1.0f + e);
  return copysignf(t, v);
}

// ---------------------------------------------------------------------------
// Setup: pack W_all (1024 x 2048) and W_hy (512 x 512) into MFMA B-fragment
// order (bf16), convert h_init to bf16, zero the barrier counter.
// Packed layout: Wp[((Jc*32 + kk)*64 + lane)*8 + e] = W_all[kk*32+(lane>>4)*8+e][Jc*16+(lane&15)]
// (any consistent lane->k bijection is correct as long as A-frags use the same one)
// ---------------------------------------------------------------------------
__global__ __launch_bounds__(256) void pack_setup(
    const float* __restrict__ Wf, const float* __restrict__ Wi,
    const float* __restrict__ Wc, const float* __restrict__ Wo,
    const float* __restrict__ Why, const float* __restrict__ hinit,
    unsigned short* __restrict__ Wp, unsigned short* __restrict__ Whyp,
    unsigned short* __restrict__ hbf0, unsigned int* __restrict__ ctr)
{
  long idx = (long)blockIdx.x * blockDim.x + threadIdx.x;
  if (idx == 0) __hip_atomic_store(ctr, 0u, __ATOMIC_RELAXED, __HIP_MEMORY_SCOPE_AGENT);
  const long NW = 1024L * 2048;   // W_all elements
  const long NY = 512L * 512;     // W_hy elements
  const long NH = 64L * 512;      // h_init elements
  if (idx < NW) {
    int e = idx & 7, l = (idx >> 3) & 63, kk = (idx >> 9) & 31;
    int Jc = (int)(idx >> 14);                   // 0..127
    int k = kk * 32 + (l >> 4) * 8 + e;          // 0..1023
    int col = Jc * 16 + (l & 15);                // 0..2047
    int g = col >> 9, j = col & 511;
    const float* W = (g == 0) ? Wf : (g == 1) ? Wi : (g == 2) ? Wc : Wo;
    Wp[idx] = (unsigned short)f2bfs(W[(long)k * 512 + j]);
  } else if (idx < NW + NY) {
    long q = idx - NW;
    int e = q & 7, l = (q >> 3) & 63, kk = (q >> 9) & 15;
    int J = (int)(q >> 13);                      // 0..31
    int k = kk * 32 + (l >> 4) * 8 + e;          // 0..511
    int col = J * 16 + (l & 15);                 // 0..511
    Whyp[q] = (unsigned short)f2bfs(Why[(long)k * 512 + col]);
  } else if (idx < NW + NY + NH) {
    long q = idx - NW - NY;
    hbf0[q] = (unsigned short)f2bfs(hinit[q]);
  }
}

// ---------------------------------------------------------------------------
// Sequential recurrence. 32 blocks x 256 threads (4 waves).
// Block jb owns hidden units [jb*16, jb*16+16) for ALL 64 batch rows and all
// 4 gates -> c update is purely register-local. One grid barrier per step.
// h double-buffered in bf16 so step-t readers never race step-t writers.
// ---------------------------------------------------------------------------
__global__ __launch_bounds__(256) void lstm_seq(
    const float* __restrict__ x,      // (B,T,D)
    const float* __restrict__ cinit,  // (B,H)
    const float* __restrict__ bf_, const float* __restrict__ bi_,
    const float* __restrict__ bc_, const float* __restrict__ bo_,
    const unsigned short* __restrict__ Wp,
    unsigned short* __restrict__ hbf0,
    unsigned short* __restrict__ hbf1,
    unsigned short* __restrict__ hs,  // (T,B,H) bf16
    float* __restrict__ tail,         // d_out + B*T*O : h_fin then c_fin
    unsigned int* __restrict__ ctr)
{
  const int jb   = blockIdx.x;
  const int tid  = threadIdx.x;
  const int wv   = tid >> 6;
  const int lane = tid & 63;
  const int lrow = lane & 15;
  const int lkg  = lane >> 4;
  const int b_arow = wv * 16 + lrow;       // A-fragment row (batch index)
  const int jcol   = jb * 16 + lrow;       // owned hidden unit (C/D col)
  const int b_cd0  = wv * 16 + lkg * 4;    // C/D row base (batch index)

  // step-invariant per-lane state
  const float vbf = bf_[jcol], vbi = bi_[jcol], vbc = bc_[jcol], vbo = bo_[jcol];
  float c0 = cinit[(long)(b_cd0 + 0) * H_ + jcol];
  float c1 = cinit[(long)(b_cd0 + 1) * H_ + jcol];
  float c2 = cinit[(long)(b_cd0 + 2) * H_ + jcol];
  float c3 = cinit[(long)(b_cd0 + 3) * H_ + jcol];

  const long aoff = (long)b_arow * H_ + lkg * 8;                 // into h buffers
  const float* xrow = x + (long)b_arow * T_ * D_ + lkg * 8;      // into x
  const unsigned short* w0 = Wp + (long)(0 * 32 + jb) * 32 * 512 + lane * 8;
  const unsigned short* w1 = Wp + (long)(1 * 32 + jb) * 32 * 512 + lane * 8;
  const unsigned short* w2 = Wp + (long)(2 * 32 + jb) * 32 * 512 + lane * 8;
  const unsigned short* w3 = Wp + (long)(3 * 32 + jb) * 32 * 512 + lane * 8;

  for (int t = 0; t < T_; ++t) {
    const unsigned short* hr = (t & 1) ? hbf1 : hbf0;  // read h_{t-1}
    unsigned short*       hw = (t & 1) ? hbf0 : hbf1;  // write h_t

    f32x4 af = {vbf, vbf, vbf, vbf};
    f32x4 ai = {vbi, vbi, vbi, vbi};
    f32x4 ac = {vbc, vbc, vbc, vbc};
    f32x4 ao = {vbo, vbo, vbo, vbo};

    // ---- h-part of concat: k in [0,512) ----
    const unsigned short* hrl = hr + aoff;
    #pragma unroll
    for (int kk = 0; kk < 16; ++kk) {
      bf16x8 a = *(const bf16x8*)(hrl + kk * 32);
      af = __builtin_amdgcn_mfma_f32_16x16x32_bf16(a, *(const bf16x8*)(w0 + kk * 512), af, 0, 0, 0);
      ai = __builtin_amdgcn_mfma_f32_16x16x32_bf16(a, *(const bf16x8*)(w1 + kk * 512), ai, 0, 0, 0);
      ac = __builtin_amdgcn_mfma_f32_16x16x32_bf16(a, *(const bf16x8*)(w2 + kk * 512), ac, 0, 0, 0);
      ao = __builtin_amdgcn_mfma_f32_16x16x32_bf16(a, *(const bf16x8*)(w3 + kk * 512), ao, 0, 0, 0);
    }
    // ---- x-part of concat: k in [512,1024) ----
    const float* xt = xrow + (long)t * D_;
    #pragma unroll
    for (int kx = 0; kx < 16; ++kx) {
      float4 xa = *(const float4*)(xt + kx * 32);
      float4 xb = *(const float4*)(xt + kx * 32 + 4);
      bf16x8 a;
      a[0] = f2bfs(xa.x); a[1] = f2bfs(xa.y); a[2] = f2bfs(xa.z); a[3] = f2bfs(xa.w);
      a[4] = f2bfs(xb.x); a[5] = f2bfs(xb.y); a[6] = f2bfs(xb.z); a[7] = f2bfs(xb.w);
      const int kk = kx + 16;
      af = __builtin_amdgcn_mfma_f32_16x16x32_bf16(a, *(const bf16x8*)(w0 + kk * 512), af, 0, 0, 0);
      ai = __builtin_amdgcn_mfma_f32_16x16x32_bf16(a, *(const bf16x8*)(w1 + kk * 512), ai, 0, 0, 0);
      ac = __builtin_amdgcn_mfma_f32_16x16x32_bf16(a, *(const bf16x8*)(w2 + kk * 512), ac, 0, 0, 0);
      ao = __builtin_amdgcn_mfma_f32_16x16x32_bf16(a, *(const bf16x8*)(w3 + kk * 512), ao, 0, 0, 0);
    }

    // ---- gates + state update (C/D: col=lane&15, row=(lane>>4)*4+i) ----
    #pragma unroll
    for (int i2 = 0; i2 < 4; ++i2) {
      float fg = sigmoid_f(af[i2]);
      float ig = sigmoid_f(ai[i2]);
      float gg = tanh_f(ac[i2]);
      float og = sigmoid_f(ao[i2]);
      float cN = (i2 == 0) ? c0 : (i2 == 1) ? c1 : (i2 == 2) ? c2 : c3;
      cN = fg * cN + ig * gg;
      float hv = og * tanh_f(cN);
      if (i2 == 0) c0 = cN; else if (i2 == 1) c1 = cN; else if (i2 == 2) c2 = cN; else c3 = cN;
      unsigned short hb = (unsigned short)f2bfs(hv);
      int brow = b_cd0 + i2;
      hw[(long)brow * H_ + jcol] = hb;
      hs[((long)t * B_ + brow) * H_ + jcol] = hb;
      if (t == T_ - 1) {
        tail[(long)brow * H_ + jcol] = hv;                    // h_fin (fp32)
        tail[(long)B_ * H_ + (long)brow * H_ + jcol] = cN;    // c_fin (fp32)
      }
    }

    // ---- grid barrier (agent-scope; 32 blocks always co-resident) ----
    __threadfence();
    __syncthreads();
    if (tid == 0) {
      __hip_atomic_fetch_add(ctr, 1u, __ATOMIC_ACQ_REL, __HIP_MEMORY_SCOPE_AGENT);
      unsigned target = (unsigned)NBLK * (unsigned)(t + 1);
      while (__hip_atomic_load(ctr, __ATOMIC_ACQUIRE, __HIP_MEMORY_SCOPE_AGENT) < target) {
        __builtin_amdgcn_s_sleep(1);
      }
    }
    __syncthreads();
  }
}

// ---------------------------------------------------------------------------
// Output projection: out(B,T,O) = hs(T,B,H) @ W_hy + b_hy.
// M = T*B = 65536 rows (m = t*64 + b, so hs row m is contiguous).
// 512 blocks x 512 threads; per block: 128 rows x all 512 cols.
// 8 waves = 2 m-groups (4 mtiles) x 4 n-groups (8 ntiles).
// ---------------------------------------------------------------------------
__global__ __launch_bounds__(512) void out_proj(
    const unsigned short* __restrict__ hs,
    const unsigned short* __restrict__ Whyp,
    const float* __restrict__ bhy,
    float* __restrict__ out)
{
  const int tid  = threadIdx.x;
  const int wv   = tid >> 6;
  const int lane = tid & 63;
  const int lrow = lane & 15;
  const int lkg  = lane >> 4;
  const int mg = wv >> 2;     // 0..1
  const int ng = wv & 3;      // 0..3
  const long mbase = (long)blockIdx.x * 128 + mg * 64;

  f32x4 acc[4][8];
  #pragma unroll
  for (int mt = 0; mt < 4; ++mt)
    #pragma unroll
    for (int nt = 0; nt < 8; ++nt) {
      float b = bhy[ng * 128 + nt * 16 + lrow];
      acc[mt][nt] = {b, b, b, b};
    }

  const unsigned short* arow = hs + (mbase + lrow) * 512 + lkg * 8;  // + mt*8192 + kk*32
  const unsigned short* bbas = Whyp + (long)(ng * 8) * 8192 + lane * 8; // + nt*8192 + kk*512

  #pragma unroll
  for (int kk = 0; kk < 16; ++kk) {
    bf16x8 a0 = *(const bf16x8*)(arow + 0 * 8192 + kk * 32);
    bf16x8 a1 = *(const bf16x8*)(arow + 1 * 8192 + kk * 32);
    bf16x8 a2 = *(const bf16x8*)(arow + 2 * 8192 + kk * 32);
    bf16x8 a3 = *(const bf16x8*)(arow + 3 * 8192 + kk * 32);
    #pragma unroll
    for (int nt = 0; nt < 8; ++nt) {
      bf16x8 bv = *(const bf16x8*)(bbas + nt * 8192 + kk * 512);
      acc[0][nt] = __builtin_amdgcn_mfma_f32_16x16x32_bf16(a0, bv, acc[0][nt], 0, 0, 0);
      acc[1][nt] = __builtin_amdgcn_mfma_f32_16x16x32_bf16(a1, bv, acc[1][nt], 0, 0, 0);
      acc[2][nt] = __builtin_amdgcn_mfma_f32_16x16x32_bf16(a2, bv, acc[2][nt], 0, 0, 0);
      acc[3][nt] = __builtin_amdgcn_mfma_f32_16x16x32_bf16(a3, bv, acc[3][nt], 0, 0, 0);
    }
  }

  // write: out[b][t][col], m = t*64 + b
  #pragma unroll
  for (int mt = 0; mt < 4; ++mt) {
    #pragma unroll
    for (int i2 = 0; i2 < 4; ++i2) {
      long m = mbase + mt * 16 + lkg * 4 + i2;
      long t = m >> 6, b = m & 63;
      float* orow = out + (b * 1024 + t) * 512;
      #pragma unroll
      for (int nt = 0; nt < 8; ++nt)
        orow[ng * 128 + nt * 16 + lrow] = acc[mt][nt][i2];
    }
  }
}

// ---------------------------------------------------------------------------
extern "C" void kernel_launch(void* const* d_in, const int* in_sizes, int n_in,
                              void* d_out, int out_size, void* d_ws, size_t ws_size,
                              hipStream_t stream) {
  const float* x      = (const float*)d_in[0];
  const float* h_init = (const float*)d_in[1];
  const float* c_init = (const float*)d_in[2];
  const float* W_f = (const float*)d_in[3];
  const float* b_f = (const float*)d_in[4];
  const float* W_i = (const float*)d_in[5];
  const float* b_i = (const float*)d_in[6];
  const float* W_c = (const float*)d_in[7];
  const float* b_c = (const float*)d_in[8];
  const float* W_o = (const float*)d_in[9];
  const float* b_o = (const float*)d_in[10];
  const float* W_hy = (const float*)d_in[11];
  const float* b_hy = (const float*)d_in[12];
  float* out = (float*)d_out;

  // ws layout (bytes)
  const size_t WP_OFF   = 0;                   // 4 MB
  const size_t WHYP_OFF = 4u << 20;            // 512 KB
  const size_t HBF0_OFF = WHYP_OFF + (512u << 10);   // 64 KB
  const size_t HBF1_OFF = HBF0_OFF + (64u << 10);    // 64 KB
  const size_t CTR_OFF  = HBF1_OFF + (64u << 10);    // 4 B (padded)
  const size_t HS_OFF   = 8u << 20;            // 64 MB
  const size_t NEED     = HS_OFF + ((size_t)T_ * B_ * H_ * 2);
  if (ws_size < NEED) return;  // scratch too small; fail visibly (absmax) rather than corrupt

  unsigned char* w = (unsigned char*)d_ws;
  unsigned short* Wp   = (unsigned short*)(w + WP_OFF);
  unsigned short* Whyp = (unsigned short*)(w + WHYP_OFF);
  unsigned short* hbf0 = (unsigned short*)(w + HBF0_OFF);
  unsigned short* hbf1 = (unsigned short*)(w + HBF1_OFF);
  unsigned int*   ctr  = (unsigned int*)(w + CTR_OFF);
  unsigned short* hs   = (unsigned short*)(w + HS_OFF);

  // 1) pack weights + init
  const long total = 1024L * 2048 + 512L * 512 + 64L * 512;
  int pgrid = (int)((total + 255) / 256);
  pack_setup<<<pgrid, 256, 0, stream>>>(W_f, W_i, W_c, W_o, W_hy, h_init,
                                        Wp, Whyp, hbf0, ctr);

  // 2) sequential recurrence
  float* tail = out + (size_t)B_ * T_ * O_;
  lstm_seq<<<NBLK, 256, 0, stream>>>(x, c_init, b_f, b_i, b_c, b_o,
                                     Wp, hbf0, hbf1, hs, tail, ctr);

  // 3) output projection
  out_proj<<<512, 512, 0, stream>>>(hs, Whyp, b_hy, out);
}

// Round 2
// 19505.281 us; speedup vs baseline: 1.0761x; 1.0761x over previous
//
#include <hip/hip_runtime.h>
#include <hip/hip_bf16.h>

#define B_ 64
#define T_ 1024
#define D_ 512
#define H_ 512
#define O_ 512
#define NBLK 32   // j-slice blocks in recurrent kernel
#define NWAVE (NBLK * 4)   // total waves signaling per step

using bf16x8 = __attribute__((ext_vector_type(8))) short;
using f32x4  = __attribute__((ext_vector_type(4))) float;

__device__ __forceinline__ short f2bfs(float f) {
  return (short)__builtin_bit_cast(unsigned short, __float2bfloat16(f));
}

__device__ __forceinline__ float sigmoid_f(float v) {
  return 1.0f / (1.0f + __expf(-v));
}
__device__ __forceinline__ float tanh_f(float v) {
  float a = fabsf(v);
  float e = __expf(-2.0f * a);
  float t = (1.0f - e) / (1.0f + e);
  return copysignf(t, v);
}

// ---------------------------------------------------------------------------
// Setup: pack W_all (1024 x 2048) and W_hy (512 x 512) into MFMA B-fragment
// order (bf16), convert h_init to bf16, zero the barrier counter.
// ---------------------------------------------------------------------------
__global__ __launch_bounds__(256) void pack_setup(
    const float* __restrict__ Wf, const float* __restrict__ Wi,
    const float* __restrict__ Wc, const float* __restrict__ Wo,
    const float* __restrict__ Why, const float* __restrict__ hinit,
    unsigned short* __restrict__ Wp, unsigned short* __restrict__ Whyp,
    unsigned short* __restrict__ hbf0, unsigned int* __restrict__ ctr)
{
  long idx = (long)blockIdx.x * blockDim.x + threadIdx.x;
  if (idx == 0) __hip_atomic_store(ctr, 0u, __ATOMIC_RELAXED, __HIP_MEMORY_SCOPE_AGENT);
  const long NW = 1024L * 2048;   // W_all elements
  const long NY = 512L * 512;     // W_hy elements
  const long NH = 64L * 512;      // h_init elements
  if (idx < NW) {
    int e = idx & 7, l = (idx >> 3) & 63, kk = (idx >> 9) & 31;
    int Jc = (int)(idx >> 14);                   // 0..127
    int k = kk * 32 + (l >> 4) * 8 + e;          // 0..1023
    int col = Jc * 16 + (l & 15);                // 0..2047
    int g = col >> 9, j = col & 511;
    const float* W = (g == 0) ? Wf : (g == 1) ? Wi : (g == 2) ? Wc : Wo;
    Wp[idx] = (unsigned short)f2bfs(W[(long)k * 512 + j]);
  } else if (idx < NW + NY) {
    long q = idx - NW;
    int e = q & 7, l = (q >> 3) & 63, kk = (q >> 9) & 15;
    int J = (int)(q >> 13);                      // 0..31
    int k = kk * 32 + (l >> 4) * 8 + e;          // 0..511
    int col = J * 16 + (l & 15);                 // 0..511
    Whyp[q] = (unsigned short)f2bfs(Why[(long)k * 512 + col]);
  } else if (idx < NW + NY + NH) {
    long q = idx - NW - NY;
    hbf0[q] = (unsigned short)f2bfs(hinit[q]);
  }
}

// ---------------------------------------------------------------------------
// Sequential recurrence. 32 blocks x 256 threads (4 waves, 1 block/CU).
// Block jb owns hidden units [jb*16, jb*16+16) for ALL 64 batch rows and all
// 4 gates -> c update is register-local. Fence-free step handoff:
//   - h published via write-through sc0|sc1 stores (lands in L3)
//   - per-WAVE relaxed atomic signal after s_waitcnt vmcnt(0)
//   - consumers poll with relaxed loads (no L2 invalidation), then read h
//     via relaxed agent-scope u64 atomic loads (L2-bypassing, L3-fresh)
//   - x-part MFMAs issued BEFORE the poll to hide the handoff latency
// ---------------------------------------------------------------------------
__global__ __launch_bounds__(256) void lstm_seq(
    const float* __restrict__ x,      // (B,T,D)
    const float* __restrict__ cinit,  // (B,H)
    const float* __restrict__ bf_, const float* __restrict__ bi_,
    const float* __restrict__ bc_, const float* __restrict__ bo_,
    const unsigned short* __restrict__ Wp,
    unsigned short* __restrict__ hbf0,
    unsigned short* __restrict__ hbf1,
    unsigned short* __restrict__ hs,  // (T,B,H) bf16
    float* __restrict__ tail,         // d_out + B*T*O : h_fin then c_fin
    unsigned int* __restrict__ ctr)
{
  const int jb   = blockIdx.x;
  const int tid  = threadIdx.x;
  const int wv   = tid >> 6;
  const int lane = tid & 63;
  const int lrow = lane & 15;
  const int lkg  = lane >> 4;
  const int b_arow = wv * 16 + lrow;       // A-fragment row (batch index)
  const int jcol   = jb * 16 + lrow;       // owned hidden unit (C/D col)
  const int b_cd0  = wv * 16 + lkg * 4;    // C/D row base (batch index)

  const float vbf = bf_[jcol], vbi = bi_[jcol], vbc = bc_[jcol], vbo = bo_[jcol];
  float c0 = cinit[(long)(b_cd0 + 0) * H_ + jcol];
  float c1 = cinit[(long)(b_cd0 + 1) * H_ + jcol];
  float c2 = cinit[(long)(b_cd0 + 2) * H_ + jcol];
  float c3 = cinit[(long)(b_cd0 + 3) * H_ + jcol];

  const long aq = (long)b_arow * 128 + lkg * 2;                  // u64 index into h buffers
  const float* xrow = x + (long)b_arow * T_ * D_ + lkg * 8;      // into x
  const unsigned short* w0 = Wp + (long)(0 * 32 + jb) * 32 * 512 + lane * 8;
  const unsigned short* w1 = Wp + (long)(1 * 32 + jb) * 32 * 512 + lane * 8;
  const unsigned short* w2 = Wp + (long)(2 * 32 + jb) * 32 * 512 + lane * 8;
  const unsigned short* w3 = Wp + (long)(3 * 32 + jb) * 32 * 512 + lane * 8;

  const unsigned long long* h0q = (const unsigned long long*)hbf0;
  const unsigned long long* h1q = (const unsigned long long*)hbf1;

  #pragma unroll 1
  for (int t = 0; t < T_; ++t) {
    f32x4 af = {vbf, vbf, vbf, vbf};
    f32x4 ai = {vbi, vbi, vbi, vbi};
    f32x4 ac = {vbc, vbc, vbc, vbc};
    f32x4 ao = {vbo, vbo, vbo, vbo};

    // ---- x-part of concat (k in [512,1024)) — independent of h_{t-1} ----
    const float* xt = xrow + (long)t * D_;
    #pragma unroll
    for (int kx = 0; kx < 16; ++kx) {
      float4 xa = *(const float4*)(xt + kx * 32);
      float4 xb = *(const float4*)(xt + kx * 32 + 4);
      bf16x8 a;
      a[0] = f2bfs(xa.x); a[1] = f2bfs(xa.y); a[2] = f2bfs(xa.z); a[3] = f2bfs(xa.w);
      a[4] = f2bfs(xb.x); a[5] = f2bfs(xb.y); a[6] = f2bfs(xb.z); a[7] = f2bfs(xb.w);
      const int kk = kx + 16;
      af = __builtin_amdgcn_mfma_f32_16x16x32_bf16(a, *(const bf16x8*)(w0 + kk * 512), af, 0, 0, 0);
      ai = __builtin_amdgcn_mfma_f32_16x16x32_bf16(a, *(const bf16x8*)(w1 + kk * 512), ai, 0, 0, 0);
      ac = __builtin_amdgcn_mfma_f32_16x16x32_bf16(a, *(const bf16x8*)(w2 + kk * 512), ac, 0, 0, 0);
      ao = __builtin_amdgcn_mfma_f32_16x16x32_bf16(a, *(const bf16x8*)(w3 + kk * 512), ao, 0, 0, 0);
    }

    // ---- wait for h_{t-1} publication (relaxed poll; no cache maintenance) ----
    const unsigned tgt = (unsigned)NWAVE * (unsigned)t;
    while (__hip_atomic_load(ctr, __ATOMIC_RELAXED, __HIP_MEMORY_SCOPE_AGENT) < tgt) {
      __builtin_amdgcn_s_sleep(1);
    }
    asm volatile("" ::: "memory");   // compiler barrier: no hoisting h loads above poll

    // ---- h-part of concat (k in [0,512)) via agent-coherent u64 loads ----
    const unsigned long long* hq = (t & 1) ? h1q : h0q;
    #pragma unroll
    for (int kk = 0; kk < 16; ++kk) {
      unsigned long long q0 = __hip_atomic_load(hq + aq + kk * 8,     __ATOMIC_RELAXED, __HIP_MEMORY_SCOPE_AGENT);
      unsigned long long q1 = __hip_atomic_load(hq + aq + kk * 8 + 1, __ATOMIC_RELAXED, __HIP_MEMORY_SCOPE_AGENT);
      union { unsigned long long q[2]; bf16x8 v; } u;
      u.q[0] = q0; u.q[1] = q1;
      af = __builtin_amdgcn_mfma_f32_16x16x32_bf16(u.v, *(const bf16x8*)(w0 + kk * 512), af, 0, 0, 0);
      ai = __builtin_amdgcn_mfma_f32_16x16x32_bf16(u.v, *(const bf16x8*)(w1 + kk * 512), ai, 0, 0, 0);
      ac = __builtin_amdgcn_mfma_f32_16x16x32_bf16(u.v, *(const bf16x8*)(w2 + kk * 512), ac, 0, 0, 0);
      ao = __builtin_amdgcn_mfma_f32_16x16x32_bf16(u.v, *(const bf16x8*)(w3 + kk * 512), ao, 0, 0, 0);
    }

    // ---- gates + state update (C/D: col=lane&15, row=(lane>>4)*4+i) ----
    unsigned short* hw = (t & 1) ? hbf0 : hbf1;
    #pragma unroll
    for (int i2 = 0; i2 < 4; ++i2) {
      float fg = sigmoid_f(af[i2]);
      float ig = sigmoid_f(ai[i2]);
      float gg = tanh_f(ac[i2]);
      float og = sigmoid_f(ao[i2]);
      float cN = (i2 == 0) ? c0 : (i2 == 1) ? c1 : (i2 == 2) ? c2 : c3;
      cN = fg * cN + ig * gg;
      float hv = og * tanh_f(cN);
      if (i2 == 0) c0 = cN; else if (i2 == 1) c1 = cN; else if (i2 == 2) c2 = cN; else c3 = cN;
      unsigned hb = (unsigned)(unsigned short)f2bfs(hv);
      int brow = b_cd0 + i2;
      // write-through, agent-coherent publish of h_t (lands in L3)
      unsigned short* hp = hw + (long)brow * H_ + jcol;
      asm volatile("global_store_short %0, %1, off sc0 sc1" :: "v"(hp), "v"(hb) : "memory");
      // streamed history for out_proj (keep L2 clean)
      __builtin_nontemporal_store((unsigned short)hb, hs + ((long)t * B_ + brow) * H_ + jcol);
      if (t == T_ - 1) {
        tail[(long)brow * H_ + jcol] = hv;                    // h_fin (fp32)
        tail[(long)B_ * H_ + (long)brow * H_ + jcol] = cN;    // c_fin (fp32)
      }
    }

    // ---- drain stores, then fence-free per-wave signal ----
    asm volatile("s_waitcnt vmcnt(0)" ::: "memory");
    if (lane == 0)
      __hip_atomic_fetch_add(ctr, 1u, __ATOMIC_RELAXED, __HIP_MEMORY_SCOPE_AGENT);
  }
}

// ---------------------------------------------------------------------------
// Output projection: out(B,T,O) = hs(T,B,H) @ W_hy + b_hy.
// ---------------------------------------------------------------------------
__global__ __launch_bounds__(512) void out_proj(
    const unsigned short* __restrict__ hs,
    const unsigned short* __restrict__ Whyp,
    const float* __restrict__ bhy,
    float* __restrict__ out)
{
  const int tid  = threadIdx.x;
  const int wv   = tid >> 6;
  const int lane = tid & 63;
  const int lrow = lane & 15;
  const int lkg  = lane >> 4;
  const int mg = wv >> 2;     // 0..1
  const int ng = wv & 3;      // 0..3
  const long mbase = (long)blockIdx.x * 128 + mg * 64;

  f32x4 acc[4][8];
  #pragma unroll
  for (int mt = 0; mt < 4; ++mt)
    #pragma unroll
    for (int nt = 0; nt < 8; ++nt) {
      float b = bhy[ng * 128 + nt * 16 + lrow];
      acc[mt][nt] = {b, b, b, b};
    }

  const unsigned short* arow = hs + (mbase + lrow) * 512 + lkg * 8;
  const unsigned short* bbas = Whyp + (long)(ng * 8) * 8192 + lane * 8;

  #pragma unroll
  for (int kk = 0; kk < 16; ++kk) {
    bf16x8 a0 = *(const bf16x8*)(arow + 0 * 8192 + kk * 32);
    bf16x8 a1 = *(const bf16x8*)(arow + 1 * 8192 + kk * 32);
    bf16x8 a2 = *(const bf16x8*)(arow + 2 * 8192 + kk * 32);
    bf16x8 a3 = *(const bf16x8*)(arow + 3 * 8192 + kk * 32);
    #pragma unroll
    for (int nt = 0; nt < 8; ++nt) {
      bf16x8 bv = *(const bf16x8*)(bbas + nt * 8192 + kk * 512);
      acc[0][nt] = __builtin_amdgcn_mfma_f32_16x16x32_bf16(a0, bv, acc[0][nt], 0, 0, 0);
      acc[1][nt] = __builtin_amdgcn_mfma_f32_16x16x32_bf16(a1, bv, acc[1][nt], 0, 0, 0);
      acc[2][nt] = __builtin_amdgcn_mfma_f32_16x16x32_bf16(a2, bv, acc[2][nt], 0, 0, 0);
      acc[3][nt] = __builtin_amdgcn_mfma_f32_16x16x32_bf16(a3, bv, acc[3][nt], 0, 0, 0);
    }
  }

  #pragma unroll
  for (int mt = 0; mt < 4; ++mt) {
    #pragma unroll
    for (int i2 = 0; i2 < 4; ++i2) {
      long m = mbase + mt * 16 + lkg * 4 + i2;
      long t = m >> 6, b = m & 63;
      float* orow = out + (b * 1024 + t) * 512;
      #pragma unroll
      for (int nt = 0; nt < 8; ++nt)
        orow[ng * 128 + nt * 16 + lrow] = acc[mt][nt][i2];
    }
  }
}

// ---------------------------------------------------------------------------
extern "C" void kernel_launch(void* const* d_in, const int* in_sizes, int n_in,
                              void* d_out, int out_size, void* d_ws, size_t ws_size,
                              hipStream_t stream) {
  const float* x      = (const float*)d_in[0];
  const float* h_init = (const float*)d_in[1];
  const float* c_init = (const float*)d_in[2];
  const float* W_f = (const float*)d_in[3];
  const float* b_f = (const float*)d_in[4];
  const float* W_i = (const float*)d_in[5];
  const float* b_i = (const float*)d_in[6];
  const float* W_c = (const float*)d_in[7];
  const float* b_c = (const float*)d_in[8];
  const float* W_o = (const float*)d_in[9];
  const float* b_o = (const float*)d_in[10];
  const float* W_hy = (const float*)d_in[11];
  const float* b_hy = (const float*)d_in[12];
  float* out = (float*)d_out;

  // ws layout (bytes)
  const size_t WP_OFF   = 0;                   // 4 MB
  const size_t WHYP_OFF = 4u << 20;            // 512 KB
  const size_t HBF0_OFF = WHYP_OFF + (512u << 10);   // 64 KB
  const size_t HBF1_OFF = HBF0_OFF + (64u << 10);    // 64 KB
  const size_t CTR_OFF  = HBF1_OFF + (64u << 10);    // 4 B (padded)
  const size_t HS_OFF   = 8u << 20;            // 64 MB
  const size_t NEED     = HS_OFF + ((size_t)T_ * B_ * H_ * 2);
  if (ws_size < NEED) return;

  unsigned char* w = (unsigned char*)d_ws;
  unsigned short* Wp   = (unsigned short*)(w + WP_OFF);
  unsigned short* Whyp = (unsigned short*)(w + WHYP_OFF);
  unsigned short* hbf0 = (unsigned short*)(w + HBF0_OFF);
  unsigned short* hbf1 = (unsigned short*)(w + HBF1_OFF);
  unsigned int*   ctr  = (unsigned int*)(w + CTR_OFF);
  unsigned short* hs   = (unsigned short*)(w + HS_OFF);

  // 1) pack weights + init
  const long total = 1024L * 2048 + 512L * 512 + 64L * 512;
  int pgrid = (int)((total + 255) / 256);
  pack_setup<<<pgrid, 256, 0, stream>>>(W_f, W_i, W_c, W_o, W_hy, h_init,
                                        Wp, Whyp, hbf0, ctr);

  // 2) sequential recurrence
  float* tail = out + (size_t)B_ * T_ * O_;
  lstm_seq<<<NBLK, 256, 0, stream>>>(x, c_init, b_f, b_i, b_c, b_o,
                                     Wp, hbf0, hbf1, hs, tail, ctr);

  // 3) output projection
  out_proj<<<512, 512, 0, stream>>>(hs, Whyp, b_hy, out);
}

// Round 3
// 19055.222 us; speedup vs baseline: 1.1016x; 1.0236x over previous
//
#include <hip/hip_runtime.h>
#include <hip/hip_bf16.h>

#define B_ 64
#define T_ 1024
#define D_ 512
#define H_ 512
#define O_ 512
#define NBLK 32   // j-slice blocks in recurrent kernel

using bf16x8 = __attribute__((ext_vector_type(8))) short;
using f32x4  = __attribute__((ext_vector_type(4))) float;

__device__ __forceinline__ short f2bfs(float f) {
  return (short)__builtin_bit_cast(unsigned short, __float2bfloat16(f));
}

__device__ __forceinline__ float sigmoid_f(float v) {
  return 1.0f / (1.0f + __expf(-v));
}
__device__ __forceinline__ float tanh_f(float v) {
  float a = fabsf(v);
  float e = __expf(-2.0f * a);
  float t = (1.0f - e) / (1.0f + e);
  return copysignf(t, v);
}

// ---------------------------------------------------------------------------
// Setup: pack W_all (1024 x 2048) and W_hy (512 x 512) into MFMA B-fragment
// order (bf16), convert h_init to bf16, zero the 32 per-block flags.
// ---------------------------------------------------------------------------
__global__ __launch_bounds__(256) void pack_setup(
    const float* __restrict__ Wf, const float* __restrict__ Wi,
    const float* __restrict__ Wc, const float* __restrict__ Wo,
    const float* __restrict__ Why, const float* __restrict__ hinit,
    unsigned short* __restrict__ Wp, unsigned short* __restrict__ Whyp,
    unsigned short* __restrict__ hbf0, unsigned int* __restrict__ flg)
{
  long idx = (long)blockIdx.x * blockDim.x + threadIdx.x;
  if (idx < NBLK) flg[idx] = 0u;               // re-zeroed every call
  const long NW = 1024L * 2048;
  const long NY = 512L * 512;
  const long NH = 64L * 512;
  if (idx < NW) {
    int e = idx & 7, l = (idx >> 3) & 63, kk = (idx >> 9) & 31;
    int Jc = (int)(idx >> 14);                   // 0..127
    int k = kk * 32 + (l >> 4) * 8 + e;          // 0..1023
    int col = Jc * 16 + (l & 15);                // 0..2047
    int g = col >> 9, j = col & 511;
    const float* W = (g == 0) ? Wf : (g == 1) ? Wi : (g == 2) ? Wc : Wo;
    Wp[idx] = (unsigned short)f2bfs(W[(long)k * 512 + j]);
  } else if (idx < NW + NY) {
    long q = idx - NW;
    int e = q & 7, l = (q >> 3) & 63, kk = (q >> 9) & 15;
    int J = (int)(q >> 13);
    int k = kk * 32 + (l >> 4) * 8 + e;
    int col = J * 16 + (l & 15);
    Whyp[q] = (unsigned short)f2bfs(Why[(long)k * 512 + col]);
  } else if (idx < NW + NY + NH) {
    long q = idx - NW - NY;
    hbf0[q] = (unsigned short)f2bfs(hinit[q]);
  }
}

// ---------------------------------------------------------------------------
// x fp32 -> bf16 streaming conversion (same (B,T,D) layout).
// ---------------------------------------------------------------------------
__global__ __launch_bounds__(256) void xconv(
    const float* __restrict__ x, unsigned short* __restrict__ xb)
{
  long i = ((long)blockIdx.x * 256 + threadIdx.x) * 8;
  float4 a = *(const float4*)(x + i);
  float4 b = *(const float4*)(x + i + 4);
  bf16x8 v;
  v[0] = f2bfs(a.x); v[1] = f2bfs(a.y); v[2] = f2bfs(a.z); v[3] = f2bfs(a.w);
  v[4] = f2bfs(b.x); v[5] = f2bfs(b.y); v[6] = f2bfs(b.z); v[7] = f2bfs(b.w);
  *(bf16x8*)(xb + i) = v;
}

// ---------------------------------------------------------------------------
// Sequential recurrence. 32 blocks x 256 threads (1 block/CU).
// Zero-RMW handoff: per-block flag store after __syncthreads-drained publish;
// consumers poll all 32 flags with one wave-parallel load. x prefetched one
// step ahead into registers (issued post-flag, consumed post-next-poll).
// X16: x already bf16 (preconverted); else fp32 + in-loop cvt.
// ---------------------------------------------------------------------------
template<bool X16>
__global__ __launch_bounds__(256, 1) void lstm_seq(
    const void* __restrict__ xv,      // (B,T,D) bf16 or fp32
    const float* __restrict__ cinit,  // (B,H)
    const float* __restrict__ bf_, const float* __restrict__ bi_,
    const float* __restrict__ bc_, const float* __restrict__ bo_,
    const unsigned short* __restrict__ Wp,
    unsigned short* __restrict__ hbf0,
    unsigned short* __restrict__ hbf1,
    unsigned short* __restrict__ hs,  // (T,B,H) bf16
    float* __restrict__ tail,         // d_out + B*T*O : h_fin then c_fin
    unsigned int* __restrict__ flg)
{
  const int jb   = blockIdx.x;
  const int tid  = threadIdx.x;
  const int wv   = tid >> 6;
  const int lane = tid & 63;
  const int lrow = lane & 15;
  const int lkg  = lane >> 4;
  const int b_arow = wv * 16 + lrow;       // A-fragment row (batch index)
  const int jcol   = jb * 16 + lrow;       // owned hidden unit (C/D col)
  const int b_cd0  = wv * 16 + lkg * 4;    // C/D row base (batch index)

  const float vbf = bf_[jcol], vbi = bi_[jcol], vbc = bc_[jcol], vbo = bo_[jcol];
  float c0 = cinit[(long)(b_cd0 + 0) * H_ + jcol];
  float c1 = cinit[(long)(b_cd0 + 1) * H_ + jcol];
  float c2 = cinit[(long)(b_cd0 + 2) * H_ + jcol];
  float c3 = cinit[(long)(b_cd0 + 3) * H_ + jcol];

  const long aq = (long)b_arow * 128 + lkg * 2;   // u64 index into h buffers
  const unsigned short* xrow16 = X16 ? (const unsigned short*)xv + (long)b_arow * T_ * D_ + lkg * 8 : nullptr;
  const float*          xrow32 = X16 ? nullptr : (const float*)xv + (long)b_arow * T_ * D_ + lkg * 8;

  const unsigned short* w0 = Wp + (long)(0 * 32 + jb) * 32 * 512 + lane * 8;
  const unsigned short* w1 = Wp + (long)(1 * 32 + jb) * 32 * 512 + lane * 8;
  const unsigned short* w2 = Wp + (long)(2 * 32 + jb) * 32 * 512 + lane * 8;
  const unsigned short* w3 = Wp + (long)(3 * 32 + jb) * 32 * 512 + lane * 8;

  const unsigned long long* h0q = (const unsigned long long*)hbf0;
  const unsigned long long* h1q = (const unsigned long long*)hbf1;

  // x prefetch registers (const-indexed after unroll -> VGPRs)
  bf16x8 xf[16];
  float4 xr[32];

  // prologue: prefetch x for t=0
  if constexpr (X16) {
    #pragma unroll
    for (int kk = 0; kk < 16; ++kk) xf[kk] = *(const bf16x8*)(xrow16 + kk * 32);
  } else {
    #pragma unroll
    for (int kk = 0; kk < 16; ++kk) {
      xr[2*kk]   = *(const float4*)(xrow32 + kk * 32);
      xr[2*kk+1] = *(const float4*)(xrow32 + kk * 32 + 4);
    }
  }

  #pragma unroll 1
  for (int t = 0; t < T_; ++t) {
    // ---- wait for all 32 blocks to have published h_{t-1} ----
    {
      const unsigned tgt = (unsigned)t;
      for (;;) {
        unsigned f = __hip_atomic_load(flg + (lane & 31), __ATOMIC_RELAXED, __HIP_MEMORY_SCOPE_AGENT);
        if (__all((int)(f >= tgt))) break;
        __builtin_amdgcn_s_sleep(1);
      }
      asm volatile("" ::: "memory");   // no hoisting h loads above poll
    }

    // ---- h loads (agent-coherent u64, L2-bypassing) ----
    const unsigned long long* hq = (t & 1) ? h1q : h0q;
    bf16x8 hf[16];
    #pragma unroll
    for (int kk = 0; kk < 16; ++kk) {
      unsigned long long q0 = __hip_atomic_load(hq + aq + kk * 8,     __ATOMIC_RELAXED, __HIP_MEMORY_SCOPE_AGENT);
      unsigned long long q1 = __hip_atomic_load(hq + aq + kk * 8 + 1, __ATOMIC_RELAXED, __HIP_MEMORY_SCOPE_AGENT);
      union { unsigned long long q[2]; bf16x8 v; } u;
      u.q[0] = q0; u.q[1] = q1;
      hf[kk] = u.v;
    }

    // ---- GEMM: h-part (k 0..511) + x-part (k 512..1023) ----
    f32x4 af = {vbf, vbf, vbf, vbf};
    f32x4 ai = {vbi, vbi, vbi, vbi};
    f32x4 ac = {vbc, vbc, vbc, vbc};
    f32x4 ao = {vbo, vbo, vbo, vbo};
    #pragma unroll
    for (int kk = 0; kk < 16; ++kk) {
      bf16x8 ah = hf[kk];
      af = __builtin_amdgcn_mfma_f32_16x16x32_bf16(ah, *(const bf16x8*)(w0 + kk * 512), af, 0, 0, 0);
      ai = __builtin_amdgcn_mfma_f32_16x16x32_bf16(ah, *(const bf16x8*)(w1 + kk * 512), ai, 0, 0, 0);
      ac = __builtin_amdgcn_mfma_f32_16x16x32_bf16(ah, *(const bf16x8*)(w2 + kk * 512), ac, 0, 0, 0);
      ao = __builtin_amdgcn_mfma_f32_16x16x32_bf16(ah, *(const bf16x8*)(w3 + kk * 512), ao, 0, 0, 0);
      bf16x8 ax;
      if constexpr (X16) {
        ax = xf[kk];
      } else {
        float4 xa = xr[2*kk], xb2 = xr[2*kk+1];
        ax[0] = f2bfs(xa.x); ax[1] = f2bfs(xa.y); ax[2] = f2bfs(xa.z); ax[3] = f2bfs(xa.w);
        ax[4] = f2bfs(xb2.x); ax[5] = f2bfs(xb2.y); ax[6] = f2bfs(xb2.z); ax[7] = f2bfs(xb2.w);
      }
      const int k2 = kk + 16;
      af = __builtin_amdgcn_mfma_f32_16x16x32_bf16(ax, *(const bf16x8*)(w0 + k2 * 512), af, 0, 0, 0);
      ai = __builtin_amdgcn_mfma_f32_16x16x32_bf16(ax, *(const bf16x8*)(w1 + k2 * 512), ai, 0, 0, 0);
      ac = __builtin_amdgcn_mfma_f32_16x16x32_bf16(ax, *(const bf16x8*)(w2 + k2 * 512), ac, 0, 0, 0);
      ao = __builtin_amdgcn_mfma_f32_16x16x32_bf16(ax, *(const bf16x8*)(w3 + k2 * 512), ao, 0, 0, 0);
    }

    // ---- gates + state update (C/D: col=lane&15, row=(lane>>4)*4+i) ----
    unsigned short* hw = (t & 1) ? hbf0 : hbf1;
    unsigned short hbv[4];
    float hvf[4], cvf[4];
    #pragma unroll
    for (int i2 = 0; i2 < 4; ++i2) {
      float fg = sigmoid_f(af[i2]);
      float ig = sigmoid_f(ai[i2]);
      float gg = tanh_f(ac[i2]);
      float og = sigmoid_f(ao[i2]);
      float cN = (i2 == 0) ? c0 : (i2 == 1) ? c1 : (i2 == 2) ? c2 : c3;
      cN = fg * cN + ig * gg;
      float hv = og * tanh_f(cN);
      if (i2 == 0) c0 = cN; else if (i2 == 1) c1 = cN; else if (i2 == 2) c2 = cN; else c3 = cN;
      hvf[i2] = hv; cvf[i2] = cN;
      unsigned hb = (unsigned)(unsigned short)f2bfs(hv);
      hbv[i2] = (unsigned short)hb;
      // write-through agent-coherent publish of h_t (lands in L3)
      unsigned short* hp = hw + (long)(b_cd0 + i2) * H_ + jcol;
      asm volatile("global_store_short %0, %1, off sc0 sc1" :: "v"(hp), "v"(hb) : "memory");
    }

    // ---- drain publishes (syncthreads implies vmcnt(0)), then ONE flag store ----
    __syncthreads();
    asm volatile("" ::: "memory");
    if (tid == 0) {
      unsigned v = (unsigned)(t + 1);
      unsigned int* p = flg + jb;
      asm volatile("global_store_dword %0, %1, off sc0 sc1" :: "v"(p), "v"(v) : "memory");
    }
    asm volatile("" ::: "memory");

    // ---- off-critical-path: history, tail, next-x prefetch ----
    #pragma unroll
    for (int i2 = 0; i2 < 4; ++i2) {
      int brow = b_cd0 + i2;
      __builtin_nontemporal_store(hbv[i2], hs + ((long)t * B_ + brow) * H_ + jcol);
      if (t == T_ - 1) {
        tail[(long)brow * H_ + jcol] = hvf[i2];
        tail[(long)B_ * H_ + (long)brow * H_ + jcol] = cvf[i2];
      }
    }
    const long tn = (t + 1 < T_) ? (t + 1) : t;
    if constexpr (X16) {
      const unsigned short* xt = xrow16 + tn * D_;
      #pragma unroll
      for (int kk = 0; kk < 16; ++kk) xf[kk] = *(const bf16x8*)(xt + kk * 32);
    } else {
      const float* xt = xrow32 + tn * D_;
      #pragma unroll
      for (int kk = 0; kk < 16; ++kk) {
        xr[2*kk]   = *(const float4*)(xt + kk * 32);
        xr[2*kk+1] = *(const float4*)(xt + kk * 32 + 4);
      }
    }
  }
}

// ---------------------------------------------------------------------------
// Output projection: out(B,T,O) = hs(T,B,H) @ W_hy + b_hy.
// ---------------------------------------------------------------------------
__global__ __launch_bounds__(512) void out_proj(
    const unsigned short* __restrict__ hs,
    const unsigned short* __restrict__ Whyp,
    const float* __restrict__ bhy,
    float* __restrict__ out)
{
  const int tid  = threadIdx.x;
  const int wv   = tid >> 6;
  const int lane = tid & 63;
  const int lrow = lane & 15;
  const int lkg  = lane >> 4;
  const int mg = wv >> 2;
  const int ng = wv & 3;
  const long mbase = (long)blockIdx.x * 128 + mg * 64;

  f32x4 acc[4][8];
  #pragma unroll
  for (int mt = 0; mt < 4; ++mt)
    #pragma unroll
    for (int nt = 0; nt < 8; ++nt) {
      float b = bhy[ng * 128 + nt * 16 + lrow];
      acc[mt][nt] = {b, b, b, b};
    }

  const unsigned short* arow = hs + (mbase + lrow) * 512 + lkg * 8;
  const unsigned short* bbas = Whyp + (long)(ng * 8) * 8192 + lane * 8;

  #pragma unroll
  for (int kk = 0; kk < 16; ++kk) {
    bf16x8 a0 = *(const bf16x8*)(arow + 0 * 8192 + kk * 32);
    bf16x8 a1 = *(const bf16x8*)(arow + 1 * 8192 + kk * 32);
    bf16x8 a2 = *(const bf16x8*)(arow + 2 * 8192 + kk * 32);
    bf16x8 a3 = *(const bf16x8*)(arow + 3 * 8192 + kk * 32);
    #pragma unroll
    for (int nt = 0; nt < 8; ++nt) {
      bf16x8 bv = *(const bf16x8*)(bbas + nt * 8192 + kk * 512);
      acc[0][nt] = __builtin_amdgcn_mfma_f32_16x16x32_bf16(a0, bv, acc[0][nt], 0, 0, 0);
      acc[1][nt] = __builtin_amdgcn_mfma_f32_16x16x32_bf16(a1, bv, acc[1][nt], 0, 0, 0);
      acc[2][nt] = __builtin_amdgcn_mfma_f32_16x16x32_bf16(a2, bv, acc[2][nt], 0, 0, 0);
      acc[3][nt] = __builtin_amdgcn_mfma_f32_16x16x32_bf16(a3, bv, acc[3][nt], 0, 0, 0);
    }
  }

  #pragma unroll
  for (int mt = 0; mt < 4; ++mt) {
    #pragma unroll
    for (int i2 = 0; i2 < 4; ++i2) {
      long m = mbase + mt * 16 + lkg * 4 + i2;
      long t = m >> 6, b = m & 63;
      float* orow = out + (b * 1024 + t) * 512;
      #pragma unroll
      for (int nt = 0; nt < 8; ++nt)
        orow[ng * 128 + nt * 16 + lrow] = acc[mt][nt][i2];
    }
  }
}

// ---------------------------------------------------------------------------
extern "C" void kernel_launch(void* const* d_in, const int* in_sizes, int n_in,
                              void* d_out, int out_size, void* d_ws, size_t ws_size,
                              hipStream_t stream) {
  const float* x      = (const float*)d_in[0];
  const float* h_init = (const float*)d_in[1];
  const float* c_init = (const float*)d_in[2];
  const float* W_f = (const float*)d_in[3];
  const float* b_f = (const float*)d_in[4];
  const float* W_i = (const float*)d_in[5];
  const float* b_i = (const float*)d_in[6];
  const float* W_c = (const float*)d_in[7];
  const float* b_c = (const float*)d_in[8];
  const float* W_o = (const float*)d_in[9];
  const float* b_o = (const float*)d_in[10];
  const float* W_hy = (const float*)d_in[11];
  const float* b_hy = (const float*)d_in[12];
  float* out = (float*)d_out;

  // ws layout (bytes)
  const size_t WP_OFF   = 0;                          // 4 MB
  const size_t WHYP_OFF = 4u << 20;                   // 512 KB
  const size_t HBF0_OFF = WHYP_OFF + (512u << 10);    // 64 KB
  const size_t HBF1_OFF = HBF0_OFF + (64u << 10);     // 64 KB
  const size_t FLG_OFF  = HBF1_OFF + (64u << 10);     // 128 B
  const size_t XB_OFF   = 8u << 20;                   // 64 MB (big path only)
  const size_t HS_BYTES = (size_t)T_ * B_ * H_ * 2;   // 64 MB
  const size_t XB_BYTES = (size_t)B_ * T_ * D_ * 2;   // 64 MB
  const size_t NEED_SMALL = (8u << 20) + HS_BYTES;            // 72 MB
  const size_t NEED_BIG   = XB_OFF + XB_BYTES + HS_BYTES;     // 136 MB
  if (ws_size < NEED_SMALL) return;
  const bool big = (ws_size >= NEED_BIG);

  unsigned char* w = (unsigned char*)d_ws;
  unsigned short* Wp   = (unsigned short*)(w + WP_OFF);
  unsigned short* Whyp = (unsigned short*)(w + WHYP_OFF);
  unsigned short* hbf0 = (unsigned short*)(w + HBF0_OFF);
  unsigned short* hbf1 = (unsigned short*)(w + HBF1_OFF);
  unsigned int*   flg  = (unsigned int*)(w + FLG_OFF);
  unsigned short* xb   = (unsigned short*)(w + XB_OFF);
  unsigned short* hs   = (unsigned short*)(w + (big ? XB_OFF + XB_BYTES : (size_t)(8u << 20)));

  // 1) pack weights + init + flag zeroing
  const long total = 1024L * 2048 + 512L * 512 + 64L * 512;
  int pgrid = (int)((total + 255) / 256);
  pack_setup<<<pgrid, 256, 0, stream>>>(W_f, W_i, W_c, W_o, W_hy, h_init,
                                        Wp, Whyp, hbf0, flg);

  // 2) optional x -> bf16 preconversion
  if (big) {
    const long nx = (long)B_ * T_ * D_;          // 33554432
    int xgrid = (int)(nx / (256 * 8));           // 16384
    xconv<<<xgrid, 256, 0, stream>>>(x, xb);
  }

  // 3) sequential recurrence
  float* tail = out + (size_t)B_ * T_ * O_;
  if (big) {
    lstm_seq<true><<<NBLK, 256, 0, stream>>>(xb, c_init, b_f, b_i, b_c, b_o,
                                             Wp, hbf0, hbf1, hs, tail, flg);
  } else {
    lstm_seq<false><<<NBLK, 256, 0, stream>>>(x, c_init, b_f, b_i, b_c, b_o,
                                              Wp, hbf0, hbf1, hs, tail, flg);
  }

  // 4) output projection
  out_proj<<<512, 512, 0, stream>>>(hs, Whyp, b_hy, out);
}

// Round 4
// 14840.646 us; speedup vs baseline: 1.4144x; 1.2840x over previous
//
#include <hip/hip_runtime.h>
#include <hip/hip_bf16.h>

#define B_ 64
#define T_ 1024
#define D_ 512
#define H_ 512
#define O_ 512
#define NBLK 32   // j-slice blocks in recurrent kernel

using bf16x8 = __attribute__((ext_vector_type(8))) short;
using f32x4  = __attribute__((ext_vector_type(4))) float;

__device__ __forceinline__ short f2bfs(float f) {
  return (short)__builtin_bit_cast(unsigned short, __float2bfloat16(f));
}

__device__ __forceinline__ float sigmoid_f(float v) {
  return 1.0f / (1.0f + __expf(-v));
}
__device__ __forceinline__ float tanh_f(float v) {
  float a = fabsf(v);
  float e = __expf(-2.0f * a);
  float t = (1.0f - e) / (1.0f + e);
  return copysignf(t, v);
}

// ---------------------------------------------------------------------------
// Setup: pack W_all (1024 x 2048) and W_hy (512 x 512) into MFMA B-fragment
// order (bf16), convert h_init to bf16, zero the 32 per-block flags.
// ---------------------------------------------------------------------------
__global__ __launch_bounds__(256) void pack_setup(
    const float* __restrict__ Wf, const float* __restrict__ Wi,
    const float* __restrict__ Wc, const float* __restrict__ Wo,
    const float* __restrict__ Why, const float* __restrict__ hinit,
    unsigned short* __restrict__ Wp, unsigned short* __restrict__ Whyp,
    unsigned short* __restrict__ hbf0, unsigned int* __restrict__ flg)
{
  long idx = (long)blockIdx.x * blockDim.x + threadIdx.x;
  if (idx < NBLK) flg[idx] = 0u;               // re-zeroed every call
  const long NW = 1024L * 2048;
  const long NY = 512L * 512;
  const long NH = 64L * 512;
  if (idx < NW) {
    int e = idx & 7, l = (idx >> 3) & 63, kk = (idx >> 9) & 31;
    int Jc = (int)(idx >> 14);                   // 0..127
    int k = kk * 32 + (l >> 4) * 8 + e;          // 0..1023
    int col = Jc * 16 + (l & 15);                // 0..2047
    int g = col >> 9, j = col & 511;
    const float* W = (g == 0) ? Wf : (g == 1) ? Wi : (g == 2) ? Wc : Wo;
    Wp[idx] = (unsigned short)f2bfs(W[(long)k * 512 + j]);
  } else if (idx < NW + NY) {
    long q = idx - NW;
    int e = q & 7, l = (q >> 3) & 63, kk = (q >> 9) & 15;
    int J = (int)(q >> 13);
    int k = kk * 32 + (l >> 4) * 8 + e;
    int col = J * 16 + (l & 15);
    Whyp[q] = (unsigned short)f2bfs(Why[(long)k * 512 + col]);
  } else if (idx < NW + NY + NH) {
    long q = idx - NW - NY;
    hbf0[q] = (unsigned short)f2bfs(hinit[q]);
  }
}

// ---------------------------------------------------------------------------
// x fp32 -> bf16 streaming conversion (same (B,T,D) layout).
// ---------------------------------------------------------------------------
__global__ __launch_bounds__(256) void xconv(
    const float* __restrict__ x, unsigned short* __restrict__ xb)
{
  long i = ((long)blockIdx.x * 256 + threadIdx.x) * 8;
  float4 a = *(const float4*)(x + i);
  float4 b = *(const float4*)(x + i + 4);
  bf16x8 v;
  v[0] = f2bfs(a.x); v[1] = f2bfs(a.y); v[2] = f2bfs(a.z); v[3] = f2bfs(a.w);
  v[4] = f2bfs(b.x); v[5] = f2bfs(b.y); v[6] = f2bfs(b.z); v[7] = f2bfs(b.w);
  *(bf16x8*)(xb + i) = v;
}

// ---------------------------------------------------------------------------
// Sequential recurrence. 32 blocks x 256 threads (1 block/CU).
// De-contended handoff: ONLY wave 0 polls the 32 per-block flags (with
// s_sleep(8) backoff); waves 1-3 park in s_barrier (no memory traffic).
// x-part MFMAs run BEFORE the poll to hide the handoff window.
// ---------------------------------------------------------------------------
template<bool X16>
__global__ __launch_bounds__(256, 1) void lstm_seq(
    const void* __restrict__ xv,      // (B,T,D) bf16 or fp32
    const float* __restrict__ cinit,  // (B,H)
    const float* __restrict__ bf_, const float* __restrict__ bi_,
    const float* __restrict__ bc_, const float* __restrict__ bo_,
    const unsigned short* __restrict__ Wp,
    unsigned short* __restrict__ hbf0,
    unsigned short* __restrict__ hbf1,
    unsigned short* __restrict__ hs,  // (T,B,H) bf16
    float* __restrict__ tail,         // d_out + B*T*O : h_fin then c_fin
    unsigned int* __restrict__ flg)
{
  const int jb   = blockIdx.x;
  const int tid  = threadIdx.x;
  const int wv   = tid >> 6;
  const int lane = tid & 63;
  const int lrow = lane & 15;
  const int lkg  = lane >> 4;
  const int b_arow = wv * 16 + lrow;       // A-fragment row (batch index)
  const int jcol   = jb * 16 + lrow;       // owned hidden unit (C/D col)
  const int b_cd0  = wv * 16 + lkg * 4;    // C/D row base (batch index)

  const float vbf = bf_[jcol], vbi = bi_[jcol], vbc = bc_[jcol], vbo = bo_[jcol];
  float c0 = cinit[(long)(b_cd0 + 0) * H_ + jcol];
  float c1 = cinit[(long)(b_cd0 + 1) * H_ + jcol];
  float c2 = cinit[(long)(b_cd0 + 2) * H_ + jcol];
  float c3 = cinit[(long)(b_cd0 + 3) * H_ + jcol];

  const long aq = (long)b_arow * 128 + lkg * 2;   // u64 index into h buffers
  const unsigned short* xrow16 = X16 ? (const unsigned short*)xv + (long)b_arow * T_ * D_ + lkg * 8 : nullptr;
  const float*          xrow32 = X16 ? nullptr : (const float*)xv + (long)b_arow * T_ * D_ + lkg * 8;

  const unsigned short* w0 = Wp + (long)(0 * 32 + jb) * 32 * 512 + lane * 8;
  const unsigned short* w1 = Wp + (long)(1 * 32 + jb) * 32 * 512 + lane * 8;
  const unsigned short* w2 = Wp + (long)(2 * 32 + jb) * 32 * 512 + lane * 8;
  const unsigned short* w3 = Wp + (long)(3 * 32 + jb) * 32 * 512 + lane * 8;

  const unsigned long long* h0q = (const unsigned long long*)hbf0;
  const unsigned long long* h1q = (const unsigned long long*)hbf1;

  // x prefetch registers (const-indexed after unroll -> VGPRs)
  bf16x8 xf[16];
  float4 xr[32];

  // prologue: prefetch x for t=0
  if constexpr (X16) {
    #pragma unroll
    for (int kk = 0; kk < 16; ++kk) xf[kk] = *(const bf16x8*)(xrow16 + kk * 32);
  } else {
    #pragma unroll
    for (int kk = 0; kk < 16; ++kk) {
      xr[2*kk]   = *(const float4*)(xrow32 + kk * 32);
      xr[2*kk+1] = *(const float4*)(xrow32 + kk * 32 + 4);
    }
  }

  #pragma unroll 1
  for (int t = 0; t < T_; ++t) {
    // ---- x-part of GEMM (k 512..1023) BEFORE the poll: hides handoff ----
    f32x4 af = {vbf, vbf, vbf, vbf};
    f32x4 ai = {vbi, vbi, vbi, vbi};
    f32x4 ac = {vbc, vbc, vbc, vbc};
    f32x4 ao = {vbo, vbo, vbo, vbo};
    #pragma unroll
    for (int kk = 0; kk < 16; ++kk) {
      bf16x8 ax;
      if constexpr (X16) {
        ax = xf[kk];
      } else {
        float4 xa = xr[2*kk], xb2 = xr[2*kk+1];
        ax[0] = f2bfs(xa.x); ax[1] = f2bfs(xa.y); ax[2] = f2bfs(xa.z); ax[3] = f2bfs(xa.w);
        ax[4] = f2bfs(xb2.x); ax[5] = f2bfs(xb2.y); ax[6] = f2bfs(xb2.z); ax[7] = f2bfs(xb2.w);
      }
      const int k2 = kk + 16;
      af = __builtin_amdgcn_mfma_f32_16x16x32_bf16(ax, *(const bf16x8*)(w0 + k2 * 512), af, 0, 0, 0);
      ai = __builtin_amdgcn_mfma_f32_16x16x32_bf16(ax, *(const bf16x8*)(w1 + k2 * 512), ai, 0, 0, 0);
      ac = __builtin_amdgcn_mfma_f32_16x16x32_bf16(ax, *(const bf16x8*)(w2 + k2 * 512), ac, 0, 0, 0);
      ao = __builtin_amdgcn_mfma_f32_16x16x32_bf16(ax, *(const bf16x8*)(w3 + k2 * 512), ao, 0, 0, 0);
    }

    // ---- handoff wait: ONLY wave 0 polls; waves 1-3 park at the barrier ----
    if (wv == 0) {
      const unsigned tgt = (unsigned)t;
      const unsigned int* fp = flg + (lane & 31);
      for (;;) {
        unsigned f;
        asm volatile("global_load_dword %0, %1, off sc0 sc1\n\ts_waitcnt vmcnt(0)"
                     : "=v"(f) : "v"(fp) : "memory");
        if (__all((int)(f >= tgt))) break;
        __builtin_amdgcn_s_sleep(8);
      }
    }
    __syncthreads();                 // release; also orders h loads after poll
    asm volatile("" ::: "memory");

    // ---- h loads (agent-coherent u64 = coalesced sc1 vector loads) ----
    const unsigned long long* hq = (t & 1) ? h1q : h0q;
    bf16x8 hf[16];
    #pragma unroll
    for (int kk = 0; kk < 16; ++kk) {
      unsigned long long q0 = __hip_atomic_load(hq + aq + kk * 8,     __ATOMIC_RELAXED, __HIP_MEMORY_SCOPE_AGENT);
      unsigned long long q1 = __hip_atomic_load(hq + aq + kk * 8 + 1, __ATOMIC_RELAXED, __HIP_MEMORY_SCOPE_AGENT);
      union { unsigned long long q[2]; bf16x8 v; } u;
      u.q[0] = q0; u.q[1] = q1;
      hf[kk] = u.v;
    }

    // ---- h-part of GEMM (k 0..511) ----
    #pragma unroll
    for (int kk = 0; kk < 16; ++kk) {
      bf16x8 ah = hf[kk];
      af = __builtin_amdgcn_mfma_f32_16x16x32_bf16(ah, *(const bf16x8*)(w0 + kk * 512), af, 0, 0, 0);
      ai = __builtin_amdgcn_mfma_f32_16x16x32_bf16(ah, *(const bf16x8*)(w1 + kk * 512), ai, 0, 0, 0);
      ac = __builtin_amdgcn_mfma_f32_16x16x32_bf16(ah, *(const bf16x8*)(w2 + kk * 512), ac, 0, 0, 0);
      ao = __builtin_amdgcn_mfma_f32_16x16x32_bf16(ah, *(const bf16x8*)(w3 + kk * 512), ao, 0, 0, 0);
    }

    // ---- gates + state update (C/D: col=lane&15, row=(lane>>4)*4+i) ----
    unsigned short* hw = (t & 1) ? hbf0 : hbf1;
    unsigned short hbv[4];
    float hvf[4], cvf[4];
    #pragma unroll
    for (int i2 = 0; i2 < 4; ++i2) {
      float fg = sigmoid_f(af[i2]);
      float ig = sigmoid_f(ai[i2]);
      float gg = tanh_f(ac[i2]);
      float og = sigmoid_f(ao[i2]);
      float cN = (i2 == 0) ? c0 : (i2 == 1) ? c1 : (i2 == 2) ? c2 : c3;
      cN = fg * cN + ig * gg;
      float hv = og * tanh_f(cN);
      if (i2 == 0) c0 = cN; else if (i2 == 1) c1 = cN; else if (i2 == 2) c2 = cN; else c3 = cN;
      hvf[i2] = hv; cvf[i2] = cN;
      unsigned hb = (unsigned)(unsigned short)f2bfs(hv);
      hbv[i2] = (unsigned short)hb;
      // write-through agent-coherent publish of h_t (lands in L3)
      unsigned short* hp = hw + (long)(b_cd0 + i2) * H_ + jcol;
      asm volatile("global_store_short %0, %1, off sc0 sc1" :: "v"(hp), "v"(hb) : "memory");
    }

    // ---- drain publishes (barrier implies vmcnt(0)), then ONE flag store ----
    __syncthreads();
    asm volatile("" ::: "memory");
    if (tid == 0) {
      unsigned v = (unsigned)(t + 1);
      unsigned int* p = flg + jb;
      asm volatile("global_store_dword %0, %1, off sc0 sc1" :: "v"(p), "v"(v) : "memory");
    }
    asm volatile("" ::: "memory");

    // ---- off-critical-path: history, tail, next-x prefetch ----
    #pragma unroll
    for (int i2 = 0; i2 < 4; ++i2) {
      int brow = b_cd0 + i2;
      __builtin_nontemporal_store(hbv[i2], hs + ((long)t * B_ + brow) * H_ + jcol);
      if (t == T_ - 1) {
        tail[(long)brow * H_ + jcol] = hvf[i2];
        tail[(long)B_ * H_ + (long)brow * H_ + jcol] = cvf[i2];
      }
    }
    const long tn = (t + 1 < T_) ? (t + 1) : t;
    if constexpr (X16) {
      const unsigned short* xt = xrow16 + tn * D_;
      #pragma unroll
      for (int kk = 0; kk < 16; ++kk) xf[kk] = *(const bf16x8*)(xt + kk * 32);
    } else {
      const float* xt = xrow32 + tn * D_;
      #pragma unroll
      for (int kk = 0; kk < 16; ++kk) {
        xr[2*kk]   = *(const float4*)(xt + kk * 32);
        xr[2*kk+1] = *(const float4*)(xt + kk * 32 + 4);
      }
    }
  }
}

// ---------------------------------------------------------------------------
// Output projection: out(B,T,O) = hs(T,B,H) @ W_hy + b_hy.
// ---------------------------------------------------------------------------
__global__ __launch_bounds__(512) void out_proj(
    const unsigned short* __restrict__ hs,
    const unsigned short* __restrict__ Whyp,
    const float* __restrict__ bhy,
    float* __restrict__ out)
{
  const int tid  = threadIdx.x;
  const int wv   = tid >> 6;
  const int lane = tid & 63;
  const int lrow = lane & 15;
  const int lkg  = lane >> 4;
  const int mg = wv >> 2;
  const int ng = wv & 3;
  const long mbase = (long)blockIdx.x * 128 + mg * 64;

  f32x4 acc[4][8];
  #pragma unroll
  for (int mt = 0; mt < 4; ++mt)
    #pragma unroll
    for (int nt = 0; nt < 8; ++nt) {
      float b = bhy[ng * 128 + nt * 16 + lrow];
      acc[mt][nt] = {b, b, b, b};
    }

  const unsigned short* arow = hs + (mbase + lrow) * 512 + lkg * 8;
  const unsigned short* bbas = Whyp + (long)(ng * 8) * 8192 + lane * 8;

  #pragma unroll
  for (int kk = 0; kk < 16; ++kk) {
    bf16x8 a0 = *(const bf16x8*)(arow + 0 * 8192 + kk * 32);
    bf16x8 a1 = *(const bf16x8*)(arow + 1 * 8192 + kk * 32);
    bf16x8 a2 = *(const bf16x8*)(arow + 2 * 8192 + kk * 32);
    bf16x8 a3 = *(const bf16x8*)(arow + 3 * 8192 + kk * 32);
    #pragma unroll
    for (int nt = 0; nt < 8; ++nt) {
      bf16x8 bv = *(const bf16x8*)(bbas + nt * 8192 + kk * 512);
      acc[0][nt] = __builtin_amdgcn_mfma_f32_16x16x32_bf16(a0, bv, acc[0][nt], 0, 0, 0);
      acc[1][nt] = __builtin_amdgcn_mfma_f32_16x16x32_bf16(a1, bv, acc[1][nt], 0, 0, 0);
      acc[2][nt] = __builtin_amdgcn_mfma_f32_16x16x32_bf16(a2, bv, acc[2][nt], 0, 0, 0);
      acc[3][nt] = __builtin_amdgcn_mfma_f32_16x16x32_bf16(a3, bv, acc[3][nt], 0, 0, 0);
    }
  }

  #pragma unroll
  for (int mt = 0; mt < 4; ++mt) {
    #pragma unroll
    for (int i2 = 0; i2 < 4; ++i2) {
      long m = mbase + mt * 16 + lkg * 4 + i2;
      long t = m >> 6, b = m & 63;
      float* orow = out + (b * 1024 + t) * 512;
      #pragma unroll
      for (int nt = 0; nt < 8; ++nt)
        orow[ng * 128 + nt * 16 + lrow] = acc[mt][nt][i2];
    }
  }
}

// ---------------------------------------------------------------------------
extern "C" void kernel_launch(void* const* d_in, const int* in_sizes, int n_in,
                              void* d_out, int out_size, void* d_ws, size_t ws_size,
                              hipStream_t stream) {
  const float* x      = (const float*)d_in[0];
  const float* h_init = (const float*)d_in[1];
  const float* c_init = (const float*)d_in[2];
  const float* W_f = (const float*)d_in[3];
  const float* b_f = (const float*)d_in[4];
  const float* W_i = (const float*)d_in[5];
  const float* b_i = (const float*)d_in[6];
  const float* W_c = (const float*)d_in[7];
  const float* b_c = (const float*)d_in[8];
  const float* W_o = (const float*)d_in[9];
  const float* b_o = (const float*)d_in[10];
  const float* W_hy = (const float*)d_in[11];
  const float* b_hy = (const float*)d_in[12];
  float* out = (float*)d_out;

  // ws layout (bytes)
  const size_t WP_OFF   = 0;                          // 4 MB
  const size_t WHYP_OFF = 4u << 20;                   // 512 KB
  const size_t HBF0_OFF = WHYP_OFF + (512u << 10);    // 64 KB
  const size_t HBF1_OFF = HBF0_OFF + (64u << 10);     // 64 KB
  const size_t FLG_OFF  = HBF1_OFF + (64u << 10);     // 128 B
  const size_t XB_OFF   = 8u << 20;                   // 64 MB (big path only)
  const size_t HS_BYTES = (size_t)T_ * B_ * H_ * 2;   // 64 MB
  const size_t XB_BYTES = (size_t)B_ * T_ * D_ * 2;   // 64 MB
  const size_t NEED_SMALL = (8u << 20) + HS_BYTES;            // 72 MB
  const size_t NEED_BIG   = XB_OFF + XB_BYTES + HS_BYTES;     // 136 MB
  if (ws_size < NEED_SMALL) return;
  const bool big = (ws_size >= NEED_BIG);

  unsigned char* w = (unsigned char*)d_ws;
  unsigned short* Wp   = (unsigned short*)(w + WP_OFF);
  unsigned short* Whyp = (unsigned short*)(w + WHYP_OFF);
  unsigned short* hbf0 = (unsigned short*)(w + HBF0_OFF);
  unsigned short* hbf1 = (unsigned short*)(w + HBF1_OFF);
  unsigned int*   flg  = (unsigned int*)(w + FLG_OFF);
  unsigned short* xb   = (unsigned short*)(w + XB_OFF);
  unsigned short* hs   = (unsigned short*)(w + (big ? XB_OFF + XB_BYTES : (size_t)(8u << 20)));

  // 1) pack weights + init + flag zeroing
  const long total = 1024L * 2048 + 512L * 512 + 64L * 512;
  int pgrid = (int)((total + 255) / 256);
  pack_setup<<<pgrid, 256, 0, stream>>>(W_f, W_i, W_c, W_o, W_hy, h_init,
                                        Wp, Whyp, hbf0, flg);

  // 2) optional x -> bf16 preconversion
  if (big) {
    const long nx = (long)B_ * T_ * D_;          // 33554432
    int xgrid = (int)(nx / (256 * 8));           // 16384
    xconv<<<xgrid, 256, 0, stream>>>(x, xb);
  }

  // 3) sequential recurrence
  float* tail = out + (size_t)B_ * T_ * O_;
  if (big) {
    lstm_seq<true><<<NBLK, 256, 0, stream>>>(xb, c_init, b_f, b_i, b_c, b_o,
                                             Wp, hbf0, hbf1, hs, tail, flg);
  } else {
    lstm_seq<false><<<NBLK, 256, 0, stream>>>(x, c_init, b_f, b_i, b_c, b_o,
                                              Wp, hbf0, hbf1, hs, tail, flg);
  }

  // 4) output projection
  out_proj<<<512, 512, 0, stream>>>(hs, Whyp, b_hy, out);
}